// Round 9
// baseline (458.380 us; speedup 1.0000x reference)
//
#include <hip/hip_runtime.h>

#define KDIM 1024
#define NOUT 15
#define NEXP 10
#define BM   64
#define NCH  8             // K chunks of 128
#define QPT  20            // 16B W-fragment groups per k-slab (K=32)
#define SCOL 305           // epilogue scratch stride (fp32)

typedef short bf16x8 __attribute__((ext_vector_type(8)));
typedef float f32x16 __attribute__((ext_vector_type(16)));

// round-to-nearest-even fp32 -> bf16 pair packed into one dword
__device__ __forceinline__ unsigned f2bf2(float a, float b) {
    unsigned ua = __float_as_uint(a);
    unsigned ub = __float_as_uint(b);
    ua = (ua + 0x7FFFu + ((ua >> 16) & 1u)) >> 16;
    ub = (ub + 0x7FFFu + ((ub >> 16) & 1u)) & 0xFFFF0000u;
    return ua | ub;
}

// barrier that lets the <=8 register x-prefetch loads ride across.
// No LDS-DMA exists in this kernel; lgkmcnt(0) publishes LDS staging writes.
__device__ __forceinline__ void kbar8() {
    __builtin_amdgcn_sched_barrier(0);
    asm volatile("s_waitcnt vmcnt(8) lgkmcnt(0)" ::: "memory");
    __builtin_amdgcn_s_barrier();
    __builtin_amdgcn_sched_barrier(0);
}

// ---- pre-pass: W (expert+gate) fp32 -> bf16 workspace in exact B-fragment order ----
// unit U (16B, 8 bf16): L = U&63, q = (U>>6)%QPT, ks = U/(QPT*64)
//   nt = q>>1 (global n-tile), kt = q&1
//   B-frag lane L holds W[row = nt*32 + (L&31)][k = ks*32 + kt*16 + (L>>5)*8 + 0..7]
__global__ void wconv_kernel(const float* __restrict__ ew,
                             const float* __restrict__ gw,
                             unsigned short* __restrict__ ws)
{
    int U  = blockIdx.x * 256 + threadIdx.x;    // 0 .. 40959
    int L  = U & 63;
    int q  = (U >> 6) % QPT;
    int ks = U / (QPT * 64);
    int nt = q >> 1, kt = q & 1;
    int wrow = nt * 32 + (L & 31);
    int wcol = ks * 32 + kt * 16 + (L >> 5) * 8;
    float4 a = {0.f,0.f,0.f,0.f}, b = {0.f,0.f,0.f,0.f};
    if (wrow < 150) {
        a = *(const float4*)(ew + wrow * KDIM + wcol);
        b = *(const float4*)(ew + wrow * KDIM + wcol + 4);
    } else if (wrow < 300) {
        a = *(const float4*)(gw + (wrow - 150) * KDIM + wcol);
        b = *(const float4*)(gw + (wrow - 150) * KDIM + wcol + 4);
    }
    uint4 o;
    o.x = f2bf2(a.x, a.y); o.y = f2bf2(a.z, a.w);
    o.z = f2bf2(b.x, b.y); o.w = f2bf2(b.z, b.w);
    *(uint4*)(ws + (size_t)U * 8) = o;
}

__global__ void __launch_bounds__(256, 3)
moe_kernel(const float* __restrict__ x,
           const unsigned short* __restrict__ wsrc,
           const float* __restrict__ eb,
           const float* __restrict__ gb,
           float* __restrict__ out)
{
    // x chunk layout: 16B units, unit(kq,row) = kq*64 + (row ^ (kq&7)),
    // kq = k_in_chunk>>3 (0..15), row 0..63. Swizzle makes BOTH the staging
    // 8B writes and the fragment ds_read_b128 conflict-light.
    __shared__ union {
        unsigned short xs[2][8192];   // 2 x 16 KB bf16 x-chunks (double buffer)
        float ep[32][SCOL];           // 39040 B epilogue scratch (after K loop)
    } sm;

    const int tid = threadIdx.x;
    const int wv  = tid >> 6;
    const int L   = tid & 63;
    const int mw  = wv >> 1;      // 0..1 : which 32-row half
    const int nw  = wv & 1;       // 0..1 : n-tiles nw*5 .. nw*5+4 (160 cols)
    const int ln  = L & 31;       // MFMA row (A) / col (B, C/D)
    const int lh  = L >> 5;       // k-half selector within fragment

    // staging: instr j covers rows 2*(wv*8+j)+{0,1}, cols (L&31)*4..+3 of a chunk
    // -> wave load = 1 KB fully contiguous (2 rows x 512B), perfectly coalesced
    const int sro = 2 * (wv * 8) + lh;         // + 2*j at use
    const int sc  = (L & 31) * 4;              // col (floats)
    const int skq = (L & 31) >> 1;             // 16B-unit kq of this lane's 4 floats
    const int sh8 = ((L & 31) & 1) * 8;        // byte half within the unit

    const float* xgb = x + (size_t)blockIdx.x * BM * KDIM;
    const bf16x8* wfL = (const bf16x8*)wsrc + L;   // per-lane W fragment base
    const int arow = mw * 32 + ln;                 // A-frag LDS row

    f32x16 acc[5];
    #pragma unroll
    for (int nt = 0; nt < 5; ++nt)
        #pragma unroll
        for (int r = 0; r < 16; ++r)
            acc[nt][r] = 0.f;

    float4 xr[8];

    auto xload = [&](int ch) {
        #pragma unroll
        for (int j = 0; j < 8; ++j)
            xr[j] = *(const float4*)(xgb + (size_t)(sro + 2 * j) * KDIM + ch * 128 + sc);
    };
    auto xwriteb = [&](unsigned short* xbuf) {
        #pragma unroll
        for (int j = 0; j < 8; ++j) {
            int r = sro + 2 * j;
            int unit = skq * 64 + (r ^ (skq & 7));
            uint2 o;
            o.x = f2bf2(xr[j].x, xr[j].y);
            o.y = f2bf2(xr[j].z, xr[j].w);
            *(uint2*)((char*)xbuf + unit * 16 + sh8) = o;
        }
    };
    auto computec = [&](int ch, const unsigned short* xbuf) {
        #pragma unroll
        for (int sl = 0; sl < 4; ++sl) {
            const int kq0 = sl * 4 + lh;
            const int kq1 = sl * 4 + 2 + lh;
            bf16x8 af0 = *(const bf16x8*)((const char*)xbuf + (kq0 * 64 + (arow ^ (kq0 & 7))) * 16);
            bf16x8 af1 = *(const bf16x8*)((const char*)xbuf + (kq1 * 64 + (arow ^ (kq1 & 7))) * 16);
            const int ks = ch * 4 + sl;
            #pragma unroll
            for (int nt = 0; nt < 5; ++nt) {
                const int q = (nw * 5 + nt) * 2;
                // per-lane coalesced B-fragment loads straight from L2-resident workspace
                bf16x8 b0 = wfL[(size_t)(ks * QPT + q) * 64];
                bf16x8 b1 = wfL[(size_t)(ks * QPT + q + 1) * 64];
                acc[nt] = __builtin_amdgcn_mfma_f32_32x32x16_bf16(af0, b0, acc[nt], 0, 0, 0);
                acc[nt] = __builtin_amdgcn_mfma_f32_32x32x16_bf16(af1, b1, acc[nt], 0, 0, 0);
            }
        }
    };

    // ---- prologue: stage chunk 0, issue chunk-1 prefetch ----
    xload(0);
    xwriteb(sm.xs[0]);
    xload(1);
    kbar8();            // 8 prefetch loads ride across

    // ---- chunk loop: 8 windows, one barrier each; W never synchronizes ----
    #pragma unroll 1
    for (int ch = 0; ch < NCH; ++ch) {
        computec(ch, sm.xs[ch & 1]);
        if (ch + 1 < NCH) {
            xwriteb(sm.xs[(ch + 1) & 1]);      // xr ready (rode 1 full chunk)
            if (ch + 2 < NCH) xload(ch + 2);   // issue next prefetch
        }
        kbar8();
    }

    // ---- epilogue: two 32-row phases through LDS scratch ----
    #pragma unroll 1
    for (int g = 0; g < 2; ++g) {
        if (mw == g) {
            // 32x32 C/D layout: col = lane&31, row = (reg&3) + 8*(reg>>2) + 4*(lane>>5)
            #pragma unroll
            for (int nt = 0; nt < 5; ++nt) {
                int col = nw * 160 + nt * 32 + ln;
                if (col < 300) {
                    #pragma unroll
                    for (int r = 0; r < 16; ++r)
                        sm.ep[(r & 3) + 8 * (r >> 2) + 4 * lh][col] = acc[nt][r];
                }
            }
        }
        __syncthreads();

        #pragma unroll 1
        for (int t = tid; t < 32 * NOUT; t += 256) {
            int row = t / NOUT, o = t % NOUT;
            float xi[NEXP], miu_v[NEXP];
            float mx = -1e30f;
            #pragma unroll
            for (int e = 0; e < NEXP; ++e) {
                miu_v[e] = sm.ep[row][e * NOUT + o]       + eb[e * NOUT + o];
                xi[e]    = sm.ep[row][150 + e * NOUT + o] + gb[e * NOUT + o];
                mx = fmaxf(mx, xi[e]);
            }
            float s = 0.f, v = 0.f;
            #pragma unroll
            for (int e = 0; e < NEXP; ++e) {
                float g2 = __expf(xi[e] - mx);
                s += g2;
                v += g2 * miu_v[e];
            }
            out[((size_t)blockIdx.x * BM + g * 32 + row) * NOUT + o] = v / s;
        }
        __syncthreads();
    }
}

extern "C" void kernel_launch(void* const* d_in, const int* in_sizes, int n_in,
                              void* d_out, int out_size, void* d_ws, size_t ws_size,
                              hipStream_t stream) {
    const float* x  = (const float*)d_in[0];
    const float* ew = (const float*)d_in[1];
    const float* eb = (const float*)d_in[2];
    const float* gw = (const float*)d_in[3];
    const float* gb = (const float*)d_in[4];
    float* out = (float*)d_out;
    unsigned short* ws = (unsigned short*)d_ws;   // NKS*QPT*64*16B = 640 KB

    wconv_kernel<<<160, 256, 0, stream>>>(ew, gw, ws);
    moe_kernel<<<65536 / BM, 256, 0, stream>>>(x, ws, eb, gb, out);
}